// Round 10
// baseline (501.845 us; speedup 1.0000x reference)
//
#include <hip/hip_runtime.h>
#include <hip/hip_bf16.h>
#include <math.h>

// Problem constants
#define Bb 2
#define Ss 2048
#define Hh 2048
#define NHh 16
#define HDd 128
#define Mm (Bb*Ss)   // 4096 tokens

typedef __bf16 bf16;
typedef __bf16 bf16x8 __attribute__((ext_vector_type(8)));
typedef __bf16 bf16x4 __attribute__((ext_vector_type(4)));
typedef float  f32x4  __attribute__((ext_vector_type(4)));

#define MFMA16(a,b,c) __builtin_amdgcn_mfma_f32_16x16x32_bf16((a),(b),(c),0,0,0)

__device__ __forceinline__ void gll16(const void* g, void* l) {
  __builtin_amdgcn_global_load_lds((__attribute__((address_space(1))) void*)g,
                                   (__attribute__((address_space(3))) void*)l, 16, 0, 0);
}

// ---------------- RoPE cos/sin tables: [S][64] each, fp32 ----------------
__global__ __launch_bounds__(256) void k_tables(float* __restrict__ cosT, float* __restrict__ sinT) {
  int id = blockIdx.x * 256 + threadIdx.x;   // S*64 threads
  int s = id >> 6, j = id & 63;
  float inv = 1.0f / powf(10000.0f, (float)j * (1.0f/64.0f));
  float a = (float)s * inv;
  cosT[id] = cosf(a);
  sinT[id] = sinf(a);
}

// ---------------- fp32 -> bf16 cast (4 elems/thread) ----------------
__global__ __launch_bounds__(256) void k_cvt(const float* __restrict__ in, bf16* __restrict__ out) {
  size_t i = ((size_t)blockIdx.x * 256 + threadIdx.x) * 4;
  float4 v = *(const float4*)(in + i);
  bf16x4 r = { (bf16)v.x, (bf16)v.y, (bf16)v.z, (bf16)v.w };
  *(bf16x4*)(out + i) = r;
}

// ---------------- GEMM: m97 structure, 128x128 tile, BK=64, 256 thr ----------------
// (r4-proven: 171 us for QKV, ~600 TF) — 8-phase 256^2 attempt regressed (r5 post-mortem:
// 2-buffer geometry caps prefetch lead at 2-3 phases < HBM latency; reverted)
// EPI=0: C fp32 row-major [M][N]
// EPI=1: QKV epilogue — cols <4096 -> QKb bf16 [M][4096]; cols >=4096 -> Vt bf16 (B,NH,HD,S)
template<int EPI>
__global__ __launch_bounds__(256) void k_gemm(
    const bf16* __restrict__ A, const bf16* __restrict__ Bw,
    float* __restrict__ C, bf16* __restrict__ QKb, bf16* __restrict__ Vt,
    int M, int N, int K)
{
  __shared__ bf16 As[128*64];
  __shared__ bf16 Bs[128*64];
  const int tid = threadIdx.x;
  const int lane = tid & 63;
  const int w = tid >> 6, wm = w & 1, wn = w >> 1;
  // XCD-aware chunked swizzle (grid % 8 == 0 for all our launches)
  const int cpx = gridDim.x >> 3;
  const int bid = (blockIdx.x & 7) * cpx + (blockIdx.x >> 3);
  const int mt = M >> 7;
  const int bm = bid % mt, bn = bid / mt;
  const int r8 = tid >> 3, c8 = tid & 7;          // staging: 32 rows/issue, 8 x 16B chunks/row
  const bf16* Ag = A  + (size_t)(bm*128 + r8) * K + c8*8;
  const bf16* Bg = Bw + (size_t)(bn*128 + r8) * K + c8*8;
  bf16* Asw = &As[r8*64 + c8*8];
  bf16* Bsw = &Bs[r8*64 + c8*8];

  f32x4 acc[4][4] = {};
  for (int k0 = 0; k0 < K; k0 += 64) {
#pragma unroll
    for (int i = 0; i < 4; ++i) {
      gll16(Ag + (size_t)i*32*K + k0, Asw + i*32*64);
      gll16(Bg + (size_t)i*32*K + k0, Bsw + i*32*64);
    }
    __syncthreads();
#pragma unroll
    for (int kc = 0; kc < 2; ++kc) {
      bf16x8 af[4], bfv[4];
#pragma unroll
      for (int mi = 0; mi < 4; ++mi)
        af[mi] = *(const bf16x8*)&As[(wm*64 + mi*16 + (lane & 15))*64 + kc*32 + (lane>>4)*8];
#pragma unroll
      for (int ni = 0; ni < 4; ++ni)
        bfv[ni] = *(const bf16x8*)&Bs[(wn*64 + ni*16 + (lane & 15))*64 + kc*32 + (lane>>4)*8];
#pragma unroll
      for (int mi = 0; mi < 4; ++mi)
#pragma unroll
        for (int ni = 0; ni < 4; ++ni)
          acc[mi][ni] = MFMA16(af[mi], bfv[ni], acc[mi][ni]);
    }
    __syncthreads();
  }
  // C/D layout: col = lane&15, row = (lane>>4)*4 + reg
  const int colB = bn*128 + wn*64;
  if (EPI == 0) {
#pragma unroll
    for (int mi = 0; mi < 4; ++mi)
#pragma unroll
      for (int ni = 0; ni < 4; ++ni) {
        int row0 = bm*128 + wm*64 + mi*16 + (lane>>4)*4;
        int col  = colB + ni*16 + (lane & 15);
#pragma unroll
        for (int r = 0; r < 4; ++r)
          C[(size_t)(row0 + r) * N + col] = acc[mi][ni][r];
      }
  } else if (colB < 4096) {   // Q or K slab -> bf16 [M][4096] (block-uniform branch)
#pragma unroll
    for (int mi = 0; mi < 4; ++mi)
#pragma unroll
      for (int ni = 0; ni < 4; ++ni) {
        int row0 = bm*128 + wm*64 + mi*16 + (lane>>4)*4;
        int col  = colB + ni*16 + (lane & 15);
#pragma unroll
        for (int r = 0; r < 4; ++r)
          QKb[(size_t)(row0 + r) * 4096 + col] = (bf16)acc[mi][ni][r];
      }
  } else {                    // V slab -> transposed bf16 (B,NH,HD,S), contiguous 8B stores
#pragma unroll
    for (int mi = 0; mi < 4; ++mi)
#pragma unroll
      for (int ni = 0; ni < 4; ++ni) {
        int row0 = bm*128 + wm*64 + mi*16 + (lane>>4)*4;
        int n2   = colB + ni*16 + (lane & 15) - 4096;   // h*128 + d
        int b = row0 >> 11, s0 = row0 & (Ss-1);
        bf16x4 pk = { (bf16)acc[mi][ni][0], (bf16)acc[mi][ni][1],
                      (bf16)acc[mi][ni][2], (bf16)acc[mi][ni][3] };
        *(bf16x4*)&Vt[((size_t)(b*NHh + (n2>>7))*HDd + (n2&127))*Ss + s0] = pk;
      }
  }
}

// ---------------- RoPE: bf16 QKb [M][4096] -> bf16 Qb (scaled), Kb in (B,S,NH,HD) ----------------
// Q scale = log2(e)/sqrt(HD): attention logits come out in base-2 units -> exp2 softmax.
__global__ __launch_bounds__(256) void k_rope(
    const bf16* __restrict__ QKb,
    const float* __restrict__ cosT, const float* __restrict__ sinT,
    bf16* __restrict__ Qb, bf16* __restrict__ Kb)
{
  const size_t id = (size_t)blockIdx.x * 256 + threadIdx.x;  // B*S*NH*64
  const int j = (int)(id & 63);
  const size_t row = id >> 6;                // tok*16 + h
  const size_t tok = row >> 4;
  const int h = (int)(row & 15);
  const int s = (int)(tok & (Ss - 1));
  const float c = cosT[s*64 + j], sn = sinT[s*64 + j];
  const size_t qbase = tok * 4096 + h * 128;
  const float scale = 0.12753102543421936f;  // log2(e)/sqrt(128)
  float q1 = (float)QKb[qbase + j],        q2 = (float)QKb[qbase + 64 + j];
  float k1 = (float)QKb[qbase + 2048 + j], k2 = (float)QKb[qbase + 2048 + 64 + j];
  const size_t obase = row * HDd;
  Qb[obase + j]      = (bf16)((q1*c - q2*sn) * scale);
  Qb[obase + 64 + j] = (bf16)((q2*c + q1*sn) * scale);
  Kb[obase + j]      = (bf16)(k1*c - k2*sn);
  Kb[obase + 64 + j] = (bf16)(k2*c + k1*sn);
}

// ---------------- Flash attention, 2-phase pipelined, lazy-softmax ----------------
// P-store/read chunk-swizzle: chunk ^= (row>>2)&7. Writer's 4 row-groups (576B apart,
// bank+16 aliasing -> was ~4-way conflict, 9.4M/dispatch) now land on distinct bank
// sets; reader pa b128 stays 16B-aligned and <=2-way (free).
__global__ __launch_bounds__(256) void k_attn(
    const bf16* __restrict__ Qb, const bf16* __restrict__ Kb,
    const bf16* __restrict__ Vt, bf16* __restrict__ Ob)
{
  __shared__ bf16 Ks[2][64*128];
  __shared__ bf16 Vs[2][128*64];
  __shared__ bf16 Ps[64*72];
  const int cpx = gridDim.x >> 3;
  const int blk = (blockIdx.x & 7) * cpx + (blockIdx.x >> 3);
  const int bh = blk >> 5;
  const int q0 = (blk & 31) * 64;
  const int b = bh >> 4, h = bh & 15;
  const int tid = threadIdx.x, lane = tid & 63, w = tid >> 6;

  const int rK = tid >> 4, cK = tid & 15;
  const int rV = tid >> 3, cV = tid & 7;
  const bf16* Kg0 = Kb + ((size_t)b*Ss*NHh + h) * HDd;
  const bf16* Vg0 = Vt + (size_t)bh * HDd * Ss;

  auto stage = [&](int bufi, int kv0) {
#pragma unroll
    for (int i = 0; i < 4; ++i) {
      const int rowK = i*16 + rK; const int sck = cK ^ (rowK & 7);
      gll16(Kg0 + (size_t)(kv0 + rowK)*(NHh*HDd) + sck*8, &Ks[bufi][rowK*128 + cK*8]);
      const int rowV = i*32 + rV; const int scv = cV ^ (rowV & 7);
      gll16(Vg0 + (size_t)rowV*Ss + kv0 + scv*8, &Vs[bufi][rowV*64 + cV*8]);
    }
  };

  bf16x8 aq[4];
  {
    const int qr = q0 + w*16 + (lane & 15);
    const bf16* qp = Qb + ((size_t)(b*Ss + qr) * NHh + h) * HDd + (lane>>4)*8;
#pragma unroll
    for (int kc = 0; kc < 4; ++kc) aq[kc] = *(const bf16x8*)(qp + kc*32);
  }
  float m_i[4], l_par[4];
  f32x4 o[8] = {};
#pragma unroll
  for (int i = 0; i < 4; ++i) { m_i[i] = -1e30f; l_par[i] = 0.f; }

  stage(0, 0);
  asm volatile("s_waitcnt vmcnt(0)" ::: "memory");
  __builtin_amdgcn_s_barrier();
  asm volatile("" ::: "memory");

  const int NT = Ss / 64;
  for (int t = 0; t < NT; ++t) {
    const int cur = t & 1;
    if (t + 1 < NT) stage(cur ^ 1, (t + 1) * 64);

    f32x4 sf[4];
    __builtin_amdgcn_s_setprio(1);
#pragma unroll
    for (int nf = 0; nf < 4; ++nf) {
      f32x4 a = {0.f,0.f,0.f,0.f};
#pragma unroll
      for (int kc = 0; kc < 4; ++kc) {
        const int row = nf*16 + (lane & 15);
        const int ch  = kc*4 + (lane>>4);
        bf16x8 bk = *(const bf16x8*)&Ks[cur][row*128 + (ch ^ (row & 7))*8];
        a = MFMA16(aq[kc], bk, a);
      }
      sf[nf] = a;
    }
    __builtin_amdgcn_s_setprio(0);

    float xl[4];
#pragma unroll
    for (int i = 0; i < 4; ++i)
      xl[i] = fmaxf(fmaxf(sf[0][i], sf[1][i]), fmaxf(sf[2][i], sf[3][i]));
    bool grow = (xl[0] > m_i[0] + 11.5f) || (xl[1] > m_i[1] + 11.5f) ||
                (xl[2] > m_i[2] + 11.5f) || (xl[3] > m_i[3] + 11.5f);
    if (__any(grow)) {
#pragma unroll
      for (int i = 0; i < 4; ++i) {
        float x = xl[i];
        x = fmaxf(x, __shfl_xor(x, 1));
        x = fmaxf(x, __shfl_xor(x, 2));
        x = fmaxf(x, __shfl_xor(x, 4));
        x = fmaxf(x, __shfl_xor(x, 8));
        float mnew = fmaxf(m_i[i], x);
        float c = exp2f(m_i[i] - mnew);
        m_i[i] = mnew; l_par[i] *= c;
#pragma unroll
        for (int nfo = 0; nfo < 8; ++nfo) o[nfo][i] *= c;
      }
    }
#pragma unroll
    for (int nf = 0; nf < 4; ++nf)
#pragma unroll
      for (int i = 0; i < 4; ++i) {
        float pv = exp2f(sf[nf][i] - m_i[i]);
        sf[nf][i] = pv;
        l_par[i] += pv;
      }
    // P -> LDS (bf16), chunk-swizzled: elem (prow,pcol) at prow*72 + (pch^((prow>>2)&7))*8 + (pcol&7)
#pragma unroll
    for (int nf = 0; nf < 4; ++nf)
#pragma unroll
      for (int i = 0; i < 4; ++i) {
        const int prow = w*16 + (lane>>4)*4 + i;
        const int pcol = nf*16 + (lane & 15);
        const int pch  = (pcol >> 3) ^ ((prow >> 2) & 7);
        Ps[prow*72 + pch*8 + (pcol & 7)] = (bf16)sf[nf][i];
      }

    __builtin_amdgcn_s_setprio(1);
#pragma unroll
    for (int kc = 0; kc < 2; ++kc) {
      const int prow = w*16 + (lane & 15);
      const int pch  = (kc*4 + (lane>>4)) ^ ((prow >> 2) & 7);
      bf16x8 pa = *(const bf16x8*)&Ps[prow*72 + pch*8];
#pragma unroll
      for (int nfo = 0; nfo < 8; ++nfo) {
        const int row = nfo*16 + (lane & 15);
        const int ch  = kc*4 + (lane>>4);
        bf16x8 bv = *(const bf16x8*)&Vs[cur][row*64 + (ch ^ (row & 7))*8];
        o[nfo] = MFMA16(pa, bv, o[nfo]);
      }
    }
    __builtin_amdgcn_s_setprio(0);

    asm volatile("s_waitcnt vmcnt(0)" ::: "memory");
    __builtin_amdgcn_s_barrier();
    asm volatile("" ::: "memory");
  }

  float linv[4];
#pragma unroll
  for (int i = 0; i < 4; ++i) {
    float s = l_par[i];
    s += __shfl_xor(s, 1); s += __shfl_xor(s, 2);
    s += __shfl_xor(s, 4); s += __shfl_xor(s, 8);
    linv[i] = 1.0f / s;
  }
#pragma unroll
  for (int nfo = 0; nfo < 8; ++nfo)
#pragma unroll
    for (int i = 0; i < 4; ++i) {
      const int qr = q0 + w*16 + (lane>>4)*4 + i;
      const int d  = nfo*16 + (lane & 15);
      Ob[((size_t)(b*Ss + qr) * NHh + h) * HDd + d] = (bf16)(o[nfo][i] * linv[i]);
    }
}

// ---------------- launcher ----------------
extern "C" void kernel_launch(void* const* d_in, const int* in_sizes, int n_in,
                              void* d_out, int out_size, void* d_ws, size_t ws_size,
                              hipStream_t stream) {
  (void)in_sizes; (void)n_in; (void)out_size; (void)ws_size;
  const float* X  = (const float*)d_in[0];
  const float* Wq = (const float*)d_in[1];
  const float* Wk = (const float*)d_in[2];
  const float* Wv = (const float*)d_in[3];
  const float* Wo = (const float*)d_in[4];
  float* out = (float*)d_out;

  char* p = (char*)d_ws;
  size_t off = 0;
  auto take = [&](size_t bytes) { char* r = p + off; off += (bytes + 255) & ~(size_t)255; return r; };

  float* cosT = (float*)take((size_t)Ss*64*4);
  float* sinT = (float*)take((size_t)Ss*64*4);
  bf16*  Xb   = (bf16*) take((size_t)Mm*Hh*2);        // 16.8 MB
  bf16*  Wqkv = (bf16*) take((size_t)3*Hh*Hh*2);      // 25.2 MB [6144][2048]
  bf16*  Wob  = (bf16*) take((size_t)Hh*Hh*2);        //  8.4 MB
  bf16*  QKb  = (bf16*) take((size_t)Mm*4096*2);      // 33.6 MB [M][4096]
  bf16*  Vt   = (bf16*) take((size_t)Mm*Hh*2);        // 16.8 MB (B,NH,HD,S)
  bf16*  Qb   = (bf16*) take((size_t)Mm*Hh*2);
  bf16*  Kb2  = (bf16*) take((size_t)Mm*Hh*2);
  bf16*  Ob   = (bf16*) take((size_t)Mm*Hh*2);

  // 1. tables + casts (Wq/Wk/Wv concatenated row-wise into Wqkv)
  k_tables<<<(Ss*64)/256, 256, 0, stream>>>(cosT, sinT);
  k_cvt<<<(Mm*Hh)/4/256, 256, 0, stream>>>(X,  Xb);
  k_cvt<<<(Hh*Hh)/4/256, 256, 0, stream>>>(Wq, Wqkv);
  k_cvt<<<(Hh*Hh)/4/256, 256, 0, stream>>>(Wk, Wqkv + (size_t)Hh*Hh);
  k_cvt<<<(Hh*Hh)/4/256, 256, 0, stream>>>(Wv, Wqkv + (size_t)2*Hh*Hh);
  k_cvt<<<(Hh*Hh)/4/256, 256, 0, stream>>>(Wo, Wob);

  // 2. fused QKV projection: Q,K -> QKb bf16; V -> Vt transposed bf16
  k_gemm<1><<<(Mm/128) * (3*Hh/128), 256, 0, stream>>>(Xb, Wqkv, nullptr, QKb, Vt, Mm, 3*Hh, Hh);
  // 3. RoPE -> bf16 Q (scaled by log2e/sqrt(HD)), K
  k_rope<<<((size_t)Mm*NHh*64)/256, 256, 0, stream>>>(QKb, cosT, sinT, Qb, Kb2);
  // 4. attention
  k_attn<<<Bb*NHh*(Ss/64), 256, 0, stream>>>(Qb, Kb2, Vt, Ob);
  // 5. output projection -> d_out (fp32)
  k_gemm<0><<<(Mm/128) * (Hh/128), 256, 0, stream>>>(Ob, Wob, out, nullptr, nullptr, Mm, Hh, Hh);
}